// Round 5
// baseline (262.706 us; speedup 1.0000x reference)
//
#include <hip/hip_runtime.h>

#define DN 384
#define DS 512
#define DMSA 64
#define DH 32
#define DP 128

typedef __bf16 bf16x8 __attribute__((ext_vector_type(8)));
typedef __bf16 bf16x4 __attribute__((ext_vector_type(4)));
typedef float f32x4 __attribute__((ext_vector_type(4)));
typedef float f32x16 __attribute__((ext_vector_type(16)));

// ws layout (bytes)
#define OFF_BT  12582912u
#define OFF_WT  25165824u   // wt bf16 [kk16 64][p 128][ks 16] = 256KB
#define OFF_INV 25427968u
#define OFF_SMF 25428224u
#define OFF_MKF 25430272u
#define OFF_WTR 25431808u   // w_hidden^T f32 [2][32][64] = 16KB

__device__ __forceinline__ void async16(const void* g, void* l) {
  __builtin_amdgcn_global_load_lds((const __attribute__((address_space(1))) unsigned*)g,
                                   (__attribute__((address_space(3))) unsigned*)l, 16, 0, 0);
}

// ---------------------------------------------------------------------------
// prep: masks, 1/num_msa, w_out -> wt [kk][p][ks] (k'=e*32+d), w_hidden^T.
// ---------------------------------------------------------------------------
__global__ __launch_bounds__(128) void prep_kernel(const void* __restrict__ mask_raw,
                                                   const void* __restrict__ msa_mask_raw,
                                                   const float* __restrict__ w_out,
                                                   const float* __restrict__ w_hidden,
                                                   __bf16* __restrict__ wt,
                                                   float* __restrict__ invp,
                                                   float* __restrict__ smf,
                                                   float* __restrict__ mkf,
                                                   float* __restrict__ wtr) {
  const int blk = blockIdx.x;
  const int tid = threadIdx.x;
  if (blk == 0) {
    __shared__ int sh[128];
    const unsigned int* u = (const unsigned int*)msa_mask_raw;
    int bad = (u[tid] > 1u) ? 1 : 0;
    sh[tid] = bad;
    __syncthreads();
    for (int off = 64; off > 0; off >>= 1) {
      if (tid < off) sh[tid] |= sh[tid + off];
      __syncthreads();
    }
    const int int_mode = (sh[0] == 0);
    __syncthreads();
    int cnt = 0;
    for (int q = tid; q < DS; q += 128) {
      float v;
      if (int_mode) v = (((const int*)msa_mask_raw)[q] != 0) ? 1.f : 0.f;
      else          v = (((const unsigned char*)msa_mask_raw)[q] != 0) ? 1.f : 0.f;
      smf[q] = v;
      cnt += (v != 0.f) ? 1 : 0;
    }
    sh[tid] = cnt;
    __syncthreads();
    for (int off = 64; off > 0; off >>= 1) {
      if (tid < off) sh[tid] += sh[tid + off];
      __syncthreads();
    }
    if (tid == 0) {
      float num = (float)sh[0];
      if (num < 1e-5f) num = 1e-5f;
      invp[0] = 1.0f / num;
    }
  } else if (blk == 1) {
    __shared__ int sh[128];
    const unsigned int* u = (const unsigned int*)mask_raw;
    int bad = 0;
    if (tid < 96) bad = (u[tid] > 1u) ? 1 : 0;
    sh[tid] = bad;
    __syncthreads();
    for (int off = 64; off > 0; off >>= 1) {
      if (tid < off) sh[tid] |= sh[tid + off];
      __syncthreads();
    }
    const int int_mode = (sh[0] == 0);
    __syncthreads();
    for (int q = tid; q < DN; q += 128) {
      float v;
      if (int_mode) v = (((const int*)mask_raw)[q] != 0) ? 1.f : 0.f;
      else          v = (((const unsigned char*)mask_raw)[q] != 0) ? 1.f : 0.f;
      mkf[q] = v;
    }
  } else if (blk == 1026) {
    // w_hidden [64][64] -> wtr: wa[c][d] = w[d][c], wb[c][d] = w[d][32+c]
    for (int idx = tid; idx < 4096; idx += 128) {
      const int d = idx >> 6, c = idx & 63;
      const float v = w_hidden[d * 64 + c];
      if (c < 32) wtr[c * 64 + d] = v;
      else        wtr[2048 + (c - 32) * 64 + d] = v;
    }
  } else {
    const int kw = blk - 2;                      // k = d*32+e
    const int p = tid;                           // 0..127
    const int kp = (kw & 31) * 32 + (kw >> 5);   // k' = e*32+d
    const int kk = kp >> 4, ks = kp & 15;
    wt[((size_t)kk * 128 + p) * 16 + ks] = (__bf16)w_out[(size_t)kw * DP + p];
  }
}

// ---------------------------------------------------------------------------
// ln_proj: LN(64) -> x@w_hidden (weights via wave-uniform scalar loads) ->
// mask/scale -> at/bt [n*32+c][s] bf16. No LDS.
// ---------------------------------------------------------------------------
__global__ __launch_bounds__(256) void ln_proj_kernel(const float* __restrict__ msa,
                                                      const float* __restrict__ gamma,
                                                      const float* __restrict__ beta,
                                                      const float* __restrict__ wtr,
                                                      const float* __restrict__ invp,
                                                      const float* __restrict__ smf,
                                                      __bf16* __restrict__ at,
                                                      __bf16* __restrict__ bt) {
  const int tid = threadIdx.x;
  const int p = blockIdx.x * 256 + tid;
  const int n = p >> 9;
  const int s = p & 511;

  const float* mp = msa + ((size_t)s * DN + n) * DMSA;
  float x[64];
  float sum = 0.f, sq = 0.f;
#pragma unroll
  for (int q = 0; q < 16; ++q) {
    float4 v = ((const float4*)mp)[q];
    x[4 * q + 0] = v.x; x[4 * q + 1] = v.y; x[4 * q + 2] = v.z; x[4 * q + 3] = v.w;
    sum += v.x + v.y + v.z + v.w;
    sq  += v.x * v.x + v.y * v.y + v.z * v.z + v.w * v.w;
  }
  const float mu = sum * (1.f / 64.f);
  const float var = sq * (1.f / 64.f) - mu * mu;
  const float rstd = rsqrtf(var + 1e-5f);
#pragma unroll
  for (int d = 0; d < 64; ++d) x[d] = (x[d] - mu) * rstd * gamma[d] + beta[d];

  const float sm = smf[s];
  const float sa = sm * invp[0];

  const size_t outbase = ((size_t)n * DH) * DS + s;
  const float* wa = wtr;
  const float* wb = wtr + 2048;
#pragma unroll
  for (int cb = 0; cb < 4; ++cb) {
    float ha[8], hb[8];
#pragma unroll
    for (int cc = 0; cc < 8; ++cc) { ha[cc] = 0.f; hb[cc] = 0.f; }
#pragma unroll
    for (int d4 = 0; d4 < 16; ++d4) {
      const float x0 = x[d4 * 4 + 0], x1 = x[d4 * 4 + 1];
      const float x2 = x[d4 * 4 + 2], x3 = x[d4 * 4 + 3];
#pragma unroll
      for (int cc = 0; cc < 8; ++cc) {
        const float4 va = *(const float4*)(wa + (cb * 8 + cc) * 64 + d4 * 4);
        const float4 vb = *(const float4*)(wb + (cb * 8 + cc) * 64 + d4 * 4);
        ha[cc] += x0 * va.x + x1 * va.y + x2 * va.z + x3 * va.w;
        hb[cc] += x0 * vb.x + x1 * vb.y + x2 * vb.z + x3 * vb.w;
      }
    }
#pragma unroll
    for (int cc = 0; cc < 8; ++cc) {
      const int c = cb * 8 + cc;
      at[outbase + (size_t)c * DS] = (__bf16)(ha[cc] * sa);
      bt[outbase + (size_t)c * DS] = (__bf16)(hb[cc] * sm);
    }
  }
}

// ---------------------------------------------------------------------------
// fused: GEMM1 256x256xK512, 16 halves (BK=32) on a 4-slot ring, 1 barrier +
// 1 counted vmcnt per half, compiler-scheduled read/MFMA overlap. Then
// op->LDS (swizzled) -> GEMM2 via 32x32x16 MFMA (1 frag/wave, wt packed
// [kk][p][16], rolling prefetch) -> pair_mask + b_out epilogue.
// ---------------------------------------------------------------------------
__global__ __launch_bounds__(512, 2) void fused_kernel(const __bf16* __restrict__ at,
                                                       const __bf16* __restrict__ bt,
                                                       const __bf16* __restrict__ wt,
                                                       const float* __restrict__ mkf,
                                                       const float* __restrict__ b_out,
                                                       float* __restrict__ out) {
  // ring: 4 slots x (A 16KB + B 16KB) = 128KB; aliased: opl 64x2064B = 129KB
  __shared__ __align__(128) char smem[132096];

  const int tid = threadIdx.x;
  const int l = tid & 63, w = tid >> 6;
  const int lr = l & 15, lk = l >> 4;
  const int wr = w >> 2, wc = w & 3;

  // XCD-aware swizzle: 48 supertiles of 8x6 blocks.
  const int orig = blockIdx.x;
  const int xcd = orig & 7, sidx = orig >> 3;
  const int stl = sidx / 48, u = sidx % 48;
  const int stg = xcd + stl * 8;
  const int stx = stg % 6, sty = stg / 6;
  const int bx = stx * 8 + (u & 7);
  const int by = sty * 6 + (u >> 3);

  // staging lane geometry (BK=32 half: row=64B=4 chunks, chunk ^= row&3)
  const int rowL = w * 32 + (l >> 2);
  const int chunkL = (l & 3) ^ ((l >> 2) & 3);
  const __bf16* gAb = at + (size_t)(bx * 256 + rowL) * 512 + chunkL * 8;
  const __bf16* gBb = bt + (size_t)(by * 256 + rowL) * 512 + chunkL * 8;

  f32x4 acc[8][4];
#pragma unroll
  for (int i = 0; i < 8; ++i)
#pragma unroll
    for (int j = 0; j < 4; ++j) acc[i][j] = (f32x4){0.f, 0.f, 0.f, 0.f};

  auto STAGE4 = [&](int h) {
    char* da = smem + (h & 3) * 32768 + w * 2048;
    char* db = da + 16384;
    const int go = h * 32;
    async16(gAb + go, da);
    async16(gAb + go + 16 * 512, da + 1024);
    async16(gBb + go, db);
    async16(gBb + go + 16 * 512, db + 1024);
  };

  STAGE4(0);
  STAGE4(1);
  STAGE4(2);

#pragma unroll
  for (int h = 0; h < 16; ++h) {
    if (h <= 13)      asm volatile("s_waitcnt vmcnt(8)" ::: "memory");
    else if (h == 14) asm volatile("s_waitcnt vmcnt(4)" ::: "memory");
    else              asm volatile("s_waitcnt vmcnt(0)" ::: "memory");
    __builtin_amdgcn_s_barrier();
    asm volatile("" ::: "memory");

    const char* A = smem + (h & 3) * 32768;
    const char* B = A + 16384;
    bf16x8 af[8], bfr[4];
#pragma unroll
    for (int fj = 0; fj < 4; ++fj) {
      const int r = wc * 64 + fj * 16 + lr;
      bfr[fj] = *(const bf16x8*)(B + r * 64 + (lk ^ (lr & 3)) * 16);
    }
#pragma unroll
    for (int fi = 0; fi < 8; ++fi) {
      const int r = wr * 128 + fi * 16 + lr;
      af[fi] = *(const bf16x8*)(A + r * 64 + (lk ^ (lr & 3)) * 16);
    }
    if (h < 13) STAGE4(h + 3);

    // no forced lgkm drain: compiler inserts fine-grained lgkmcnt per MFMA;
    // all reads are consumed before the next barrier (in-order LDS returns).
#pragma unroll
    for (int fi = 0; fi < 8; ++fi)
#pragma unroll
      for (int fj = 0; fj < 4; ++fj)
        acc[fi][fj] = __builtin_amdgcn_mfma_f32_16x16x32_bf16(af[fi], bfr[fj], acc[fi][fj], 0, 0, 0);
    asm volatile("" ::: "memory");
  }

  // all waves past their last reads before op-writes clobber the ring
  __builtin_amdgcn_s_barrier();
  asm volatile("" ::: "memory");

  // ---- op tile -> LDS bf16 as A2[pair][k'=e*32+d], chunk-XOR swizzled ----
#pragma unroll
  for (int fi = 0; fi < 8; ++fi) {
    const int i_l = wr * 4 + (fi >> 1);
#pragma unroll
    for (int fj = 0; fj < 4; ++fj) {
      const int col = wc * 64 + fj * 16 + lr;
      const int j_l = col >> 5, e = col & 31;
      const int pair = i_l * 8 + j_l;
      const int cw = e * 4 + (fi & 1) * 2 + (lk >> 1);
      const int phys = cw ^ (e & 7);
      bf16x4 pk;
      pk[0] = (__bf16)acc[fi][fj][0];
      pk[1] = (__bf16)acc[fi][fj][1];
      pk[2] = (__bf16)acc[fi][fj][2];
      pk[3] = (__bf16)acc[fi][fj][3];
      *(bf16x4*)(smem + pair * 2064 + phys * 16 + (lk & 1) * 8) = pk;
    }
  }

  // GEMM2 geometry + first B-frag prefetch (hides L2 latency under barrier)
  const int mf = w >> 2, pf = w & 3;
  const int l31 = l & 31, lh = l >> 5;
  const __bf16* wb = wt + (size_t)(pf * 32 + l31) * 16 + lh * 8;  // + kk*2048
  bf16x8 b2 = *(const bf16x8*)(wb);

  asm volatile("s_waitcnt lgkmcnt(0)" ::: "memory");
  __builtin_amdgcn_s_barrier();
  asm volatile("" ::: "memory");

  // ---- GEMM2: C2[64 pairs][128 p], K=1024, 32x32x16 MFMA, 1 frag/wave ----
  f32x16 acc2;
#pragma unroll
  for (int q = 0; q < 16; ++q) acc2[q] = 0.f;

  const char* aBase = smem + (mf * 32 + l31) * 2064;
#pragma unroll 4
  for (int kk = 0; kk < 64; ++kk) {
    bf16x8 b2n;
    if (kk < 63) b2n = *(const bf16x8*)(wb + (size_t)(kk + 1) * 2048);
    const int cw = kk * 2 + lh;
    const int phys = cw ^ ((kk >> 1) & 7);
    const bf16x8 a2 = *(const bf16x8*)(aBase + phys * 16);
    acc2 = __builtin_amdgcn_mfma_f32_32x32x16_bf16(a2, b2, acc2, 0, 0, 0);
    b2 = b2n;
  }

  const int p = pf * 32 + l31;
  const float bo = b_out[p];
#pragma unroll
  for (int reg = 0; reg < 16; ++reg) {
    const int pair = mf * 32 + (reg & 3) + 8 * (reg >> 2) + 4 * lh;
    const int i = bx * 8 + (pair >> 3);
    const int j = by * 8 + (pair & 7);
    const float pm = mkf[i] * mkf[j];
    out[((size_t)i * DN + j) * DP + p] = acc2[reg] * pm + bo;
  }
}

extern "C" void kernel_launch(void* const* d_in, const int* in_sizes, int n_in,
                              void* d_out, int out_size, void* d_ws, size_t ws_size,
                              hipStream_t stream) {
  const float* msa      = (const float*)d_in[0];
  const void*  mask     = d_in[1];
  const void*  msa_mask = d_in[2];
  const float* gamma    = (const float*)d_in[3];
  const float* beta     = (const float*)d_in[4];
  const float* w_hidden = (const float*)d_in[5];
  const float* w_out    = (const float*)d_in[6];
  const float* b_out    = (const float*)d_in[7];
  float* out = (float*)d_out;

  char* ws = (char*)d_ws;
  __bf16* at  = (__bf16*)ws;
  __bf16* bt  = (__bf16*)(ws + OFF_BT);
  __bf16* wt  = (__bf16*)(ws + OFF_WT);
  float*  inv = (float*)(ws + OFF_INV);
  float*  smf = (float*)(ws + OFF_SMF);
  float*  mkf = (float*)(ws + OFF_MKF);
  float*  wtr = (float*)(ws + OFF_WTR);

  prep_kernel<<<1027, 128, 0, stream>>>(mask, msa_mask, w_out, w_hidden, wt, inv, smf, mkf, wtr);
  ln_proj_kernel<<<768, 256, 0, stream>>>(msa, gamma, beta, wtr, inv, smf, at, bt);
  fused_kernel<<<2304, 512, 0, stream>>>(at, bt, wt, mkf, b_out, out);
}